// Round 10
// baseline (415.348 us; speedup 1.0000x reference)
//
#include <hip/hip_runtime.h>

using u16 = unsigned short;
typedef __attribute__((ext_vector_type(8))) short short8;
typedef __attribute__((ext_vector_type(4))) float f32x4;

__device__ __forceinline__ u16 f2bf(float f) {
  unsigned int u = __float_as_uint(f);
  u = (u + 0x7FFFu + ((u >> 16) & 1u)) >> 16;   // RNE, fine for non-NaN
  return (u16)u;
}
__device__ __forceinline__ float bf2f(u16 v) {
  return __uint_as_float(((unsigned int)v) << 16);
}

// async global->LDS, 16B per lane. LDS dest is wave-uniform base + lane*16.
__device__ __forceinline__ void gload16(const void* g, void* l) {
  __builtin_amdgcn_global_load_lds((const __attribute__((address_space(1))) void*)g,
                                   (__attribute__((address_space(3))) void*)l, 16, 0, 0);
}

#define B_ 4
#define S_ 4096
#define D_ 1024
#define H_ 16
#define HD_ 64
#define M_ (B_*S_)    // 16384
#define N1_ (3*D_)    // 3072

// workspace layout (bytes) -- historical region map; new buffers alias dead regions.
#define OFF_XB    0ull                                  // x bf16 [M][1024]
#define OFF_WQKVT (OFF_XB    + (size_t)M_*D_*2)         // Wqkv^T bf16 [3072][1024]
#define OFF_WOT   (OFF_WQKVT + (size_t)N1_*D_*2)        // Wo^T bf16 [1024][1024]
#define OFF_QBUF  (OFF_WOT   + (size_t)D_*D_*2)         // Q~ bf16 [M][1024] (elu+1, pre-scaled)
#define OFF_KT    (OFF_QBUF  + (size_t)M_*D_*2)         // 32 MB region
#define OFF_VT    (OFF_KT    + (size_t)M_*D_*2)         // 32 MB region
#define OFF_KV    (OFF_VT    + (size_t)M_*D_*2)         // 4 MB region (legacy)
#define OFF_KSUM  (OFF_KV    + (size_t)4*64*4096*4)
#define WS_NEEDED (OFF_KSUM  + (size_t)4*64*64*4)
// aliases:
#define OFF_WT    OFF_KT                                 // W~T bf16 [4][1024][1024] = 8 MB
#define OFF_KSG   (OFF_KT + ((size_t)9<<20))             // Ksum fp32 [64 bh][64] = 16 KB
#define OFF_KVPP  OFF_VT                                 // KV partials fp32 [64 mb][16 h][4096] = 16 MB
#define OFF_KSPP  (OFF_VT + ((size_t)16<<20))            // Ksum partials fp32 [64 mb][16 h][64] = 256 KB
#define OFF_CNT   (OFF_VT + ((size_t)17<<20))            // last-block counters int [32] = 128 B

// ---------------- merged prep: x->bf16, Wqkv^T, Wo^T, counter zero ----------------
__global__ __launch_bounds__(256) void prep_kernel(const float* __restrict__ x, u16* __restrict__ xb,
                                                   const float* __restrict__ Wqkv, u16* __restrict__ wqkvt,
                                                   const float* __restrict__ Wo, u16* __restrict__ wot,
                                                   int* __restrict__ cnt)
{
  __shared__ float tile[32][33];
  int bid = blockIdx.x, tid = threadIdx.x;
  if (bid >= 20480) {                        // counter-zero block (runs each iteration)
    if (tid < 32) cnt[tid] = 0;
    return;
  }
  if (bid < 16384) {
    int i = bid * 256 + tid;               // n4 = M_*D_/4 = 4194304 = 16384*256 exactly
    float4 v = ((const float4*)x)[i];
    uint2 o;
    o.x = (unsigned)f2bf(v.x) | ((unsigned)f2bf(v.y) << 16);
    o.y = (unsigned)f2bf(v.z) | ((unsigned)f2bf(v.w) << 16);
    ((uint2*)xb)[i] = o;
    return;
  }
  const float* in; u16* out; int R, C, cb, rb;
  if (bid < 19456) {
    int t = bid - 16384;  in = Wqkv; out = wqkvt; R = D_; C = N1_;
    cb = t % 96; rb = t / 96;
  } else {
    int t = bid - 19456;  in = Wo; out = wot; R = D_; C = D_;
    cb = t % 32; rb = t / 32;
  }
  int tx = tid & 31, ty = tid >> 5;
  int c0 = cb * 32, r0 = rb * 32;
#pragma unroll
  for (int i = 0; i < 4; i++)
    tile[ty + i*8][tx] = in[(size_t)(r0 + ty + i*8) * C + c0 + tx];
  __syncthreads();
#pragma unroll
  for (int i = 0; i < 4; i++)
    out[(size_t)(c0 + ty + i*8) * R + r0 + tx] = f2bf(tile[tx][ty + i*8]);
}

// ---------------- main GEMM: 256x256 tile, BK=32, ring-4 LDS pipeline ----------------
// C[M,N] = A[M,K](bf16) * Bt[N,K](bf16)^T.  512 thr = 8 waves (2M x 4N); acc 8x4 frags.
// MODE is compile-time (r6 lesson: runtime mode in the address chain cost 27%).
// MODE 4: Q qkv (grid.x=4) with FUSED per-head normalizer: each wave's 64-col
//         subtile = one head -> n_h per row via lane-partial dot + 4x shfl_xor
//         (l16-group = one row), then scaled elu+1 Q~ -> qout. Needs Ks (ksg).
// MODE 3: KV-fused qkv (grid.x=8=head-pair p): B rows {1024+p*128 (K), +1024 (V)};
//         epilogue writes K(elu)/V tiles to smem (main-loop layout), computes
//         head-blocked KV + Ksum via MFMA, plain-stores per-M-block partials;
//         THEN last-block-per-(b,p) (threadfence+atomic counter, 16 arrivals)
//         sums the 16 partials and computes the W~T slice + ksg inline
//         (kvw kernel absorbed; r9 change).
// MODE 2: out-proj (grid.x=4): per-batch B base (bm>>12)<<20 elems; fp32 C store.
// REGISTER NOTE: acc[8][4] = 128 unified regs alone -> NEVER set min-waves > 2
// (r4 lesson: launch_bounds(512,4) caps unified VGPR+AGPR at 128 -> spill, 13x slower).
// Ring-4 ledger: stage t+3 into slot (t+3)&3 (freed by barrier of t-1); end-of-step
// vmcnt(8) -> tile t+1 landed, t+2/t+3 in flight; drain tail 8/4/0.
// LDS per 16KB panel: paired rows [128 phys rows][8 chunks of 16B];
// logical (r,kchunk) at phys chunk pch = (((r&1)<<2)|kchunk) ^ ((r>>1)&7).
// XOR involution applied to global fetch addr on staging and ds_read addr on frag
// read -> conflict-free (verified: 0 bank conflicts in main loop).
template<int MODE>
__global__ __launch_bounds__(512, 2) void gemm256(
    const u16* __restrict__ A, const u16* __restrict__ Bt,
    float* __restrict__ Cf, u16* __restrict__ qout,
    float* __restrict__ P1, float* __restrict__ P2,
    const float* __restrict__ Ks,
    const u16* __restrict__ wotp, u16* __restrict__ wtp,
    float* __restrict__ ksgp, int* __restrict__ cnt,
    int M, int N, int K)
{
  __shared__ __align__(16) char smem[131072];   // [4 slots][A 16KB] + [4 slots][B 16KB]
  __shared__ int lastFlag;
  int tid = threadIdx.x;
  int w = tid >> 6, lane = tid & 63;
  int quad = lane >> 4, l16 = lane & 15;
  int wm = w >> 2, wn = w & 3;

  // XCD-aware bijective swizzle (nwg % 8 == 0). Blocks with flat%8==x get a
  // contiguous wg chunk -> by-grouped per XCD -> A panel 4MB/XCD (L2-fit).
  int nwg = gridDim.x * gridDim.y;
  int flat = blockIdx.y * gridDim.x + blockIdx.x;
  int wg = (flat & 7) * (nwg >> 3) + (flat >> 3);
  int bx = wg % gridDim.x, by = wg / gridDim.x;
  int bm = by * 256, bn = bx * 256;

  // staging: lane covers LDS bytes lane*16 in its wave's 1KB strip; inverse swizzle
  // goes into the global source address (rule #21: linear dest + inverse-swz source).
  int prl = lane >> 3;                          // phys row-in-strip 0..7
  int c4  = (lane & 7) ^ prl;                   // logical chunk 0..7
  int r0  = ((w << 3) + prl) * 2 + (c4 >> 2);   // logical row 0..127
  int koff = (c4 & 3) * 8;                      // logical k element offset
  const u16* gA0 = A + (size_t)(bm + r0) * K + koff;
  const u16* gB0;
  size_t rowskipA = (size_t)128 * K;
  size_t rowskipB;
  if constexpr (MODE == 3) {
    gB0 = Bt + (size_t)(1024 + bx * 128 + r0) * K + koff;   // K rows; +rowskipB = V rows
    rowskipB = (size_t)1024 * K;
  } else if constexpr (MODE == 2) {
    gB0 = Bt + ((size_t)(bm >> 12) << 20) + (size_t)(bn + r0) * K + koff;
    rowskipB = (size_t)128 * K;
  } else {
    gB0 = Bt + (size_t)(bn + r0) * K + koff;
    rowskipB = (size_t)128 * K;
  }
  char* smemc = smem;
  int ldsAw = w * 1024;                         // wave-uniform LDS bases
  int ldsBw = 65536 + w * 1024;

  // fragment read bases: pr&7 = (l16>>1)&7 (mi*8, wm*64 vanish mod 8)
  int ph = (((l16 & 1) << 2) | quad) ^ ((l16 >> 1) & 7);
  int baseA = wm * 8192 + (l16 >> 1) * 128 + ph * 16;
  int baseB = 65536 + wn * 4096 + (l16 >> 1) * 128 + ph * 16;

  f32x4 acc[8][4];
#pragma unroll
  for (int i = 0; i < 8; i++)
#pragma unroll
    for (int j = 0; j < 4; j++) acc[i][j] = (f32x4)0.0f;

  int nt = K >> 5;   // K=1024 -> 32 steps

#define STG(tt, slot) {                                                   \
    const u16* a0_ = gA0 + (tt) * 32;                                     \
    const u16* b0_ = gB0 + (tt) * 32;                                     \
    gload16(a0_,            smemc + (slot)*16384 + ldsAw);                \
    gload16(a0_ + rowskipA, smemc + (slot)*16384 + 8192 + ldsAw);         \
    gload16(b0_,            smemc + (slot)*16384 + ldsBw);                \
    gload16(b0_ + rowskipB, smemc + (slot)*16384 + 8192 + ldsBw);         \
  }

#define COMPUTE(slot) {                                                              \
    const char* sb = smemc + (slot) * 16384;                                         \
    short8 bfr[4], af[8];                                                            \
    _Pragma("unroll")                                                                \
    for (int nj = 0; nj < 4; nj++) bfr[nj] = *(const short8*)(sb + baseB + nj*1024); \
    _Pragma("unroll")                                                                \
    for (int mi = 0; mi < 8; mi++) af[mi] = *(const short8*)(sb + baseA + mi*1024);  \
    __builtin_amdgcn_s_setprio(1);                                                   \
    _Pragma("unroll")                                                                \
    for (int mi = 0; mi < 8; mi++)                                                   \
      _Pragma("unroll")                                                              \
      for (int nj = 0; nj < 4; nj++)                                                 \
        acc[mi][nj] = __builtin_amdgcn_mfma_f32_16x16x32_bf16(af[mi], bfr[nj],       \
                                                              acc[mi][nj], 0, 0, 0); \
    __builtin_amdgcn_s_setprio(0);                                                   \
  }

#define WAITBAR(n) {                                                      \
    asm volatile("s_waitcnt vmcnt(" #n ")" ::: "memory");                 \
    __builtin_amdgcn_s_barrier();                                         \
    asm volatile("" ::: "memory");                                        \
  }

  // prologue: 3 tiles in flight; wait for tile 0 only
  STG(0, 0); STG(1, 1); STG(2, 2);
  WAITBAR(8)

  // main loop: steps 0 .. nt-5; STG(t+3) always valid (t+3 <= nt-2)
  for (int tb = 0; tb < nt - 4; tb += 4) {
#pragma unroll
    for (int i = 0; i < 4; ++i) {
      int t = tb + i;
      STG(t + 3, ((i + 3) & 3));        // slot (t-1)&3: freed by preceding barrier
      COMPUTE(i)
      WAITBAR(8)                        // t+2, t+3 stay in flight; t+1 landed
    }
  }

  // drain tail: steps nt-4 .. nt-1 in slots 0..3, wait counts shrink 8/4/0
  STG(nt - 1, 3);                       // slot 3 freed by last main-loop barrier
  COMPUTE(0)
  WAITBAR(8)                            // nt-3,nt-2,nt-1 outstanding(12) -> nt-3 landed
  COMPUTE(1)
  WAITBAR(4)                            // nt-2,nt-1 outstanding(8) -> nt-2 landed
  COMPUTE(2)
  WAITBAR(0)                            // nt-1 landed
  COMPUTE(3)

#undef STG
#undef COMPUTE
#undef WAITBAR

  // C/D layout: col = lane&15 (+nj*16), row = quad*4 + reg (verified m89/m91)
  if constexpr (MODE == 2) {
    int colbase = bn + wn * 64;
#pragma unroll
    for (int mi = 0; mi < 8; mi++) {
      int row0 = bm + wm * 128 + mi * 16 + quad * 4;
#pragma unroll
      for (int nj = 0; nj < 4; nj++) {
        int col = colbase + nj * 16 + l16;
#pragma unroll
        for (int r = 0; r < 4; r++)
          Cf[(size_t)(row0 + r) * N + col] = acc[mi][nj][r];
      }
    }
  } else if constexpr (MODE == 4) {
    // Q with fused per-head normalizer scale. colbase is one full head.
    int colbase = bn + wn * 64;
    int b = bm >> 12;
    int h = colbase >> 6;
    float ksv[4];
#pragma unroll
    for (int nj = 0; nj < 4; nj++)
      ksv[nj] = Ks[(b * 16 + h) * 64 + nj * 16 + l16];
#pragma unroll
    for (int mi = 0; mi < 8; mi++) {
      float vv[4][4], nrm[4];
#pragma unroll
      for (int r = 0; r < 4; r++) nrm[r] = 0.0f;
#pragma unroll
      for (int nj = 0; nj < 4; nj++)
#pragma unroll
        for (int r = 0; r < 4; r++) {
          float v = acc[mi][nj][r];
          v = (v > 0.0f) ? (v + 1.0f) : __expf(v);   // elu+1
          vv[nj][r] = v;
          nrm[r] += v * ksv[nj];
        }
      // reduce over the 16 l16-lanes (same row, 64 cols of the head)
#pragma unroll
      for (int r = 0; r < 4; r++) {
        nrm[r] += __shfl_xor(nrm[r], 1);
        nrm[r] += __shfl_xor(nrm[r], 2);
        nrm[r] += __shfl_xor(nrm[r], 4);
        nrm[r] += __shfl_xor(nrm[r], 8);
        nrm[r] = 1.0f / (nrm[r] + 1e-6f);
      }
      int row0 = bm + wm * 128 + mi * 16 + quad * 4;
#pragma unroll
      for (int nj = 0; nj < 4; nj++) {
        int col = colbase + nj * 16 + l16;
#pragma unroll
        for (int r = 0; r < 4; r++)
          qout[(size_t)(row0 + r) * D_ + col] = f2bf(vv[nj][r] * nrm[r]);
      }
    }
  } else {   // MODE 3: fused KV + Ksum (+ last-block W~T/ksg reduction)
    __syncthreads();   // all waves done with slot-3 ds_reads before smem reuse
    // 1) write K(elu)/V tiles to smem in the main-loop paired-row layout:
    //    8 s-slots x [128 rows][32 s], K at 0, V at 65536.
    {
      char* basekv = smemc + ((wn < 2) ? 0 : 65536);
      bool doElu = (wn < 2);
#pragma unroll
      for (int mi = 0; mi < 8; mi++) {
        int sb = wm * 128 + mi * 16 + quad * 4;
        int slot = sb >> 5;
        int kc = (sb >> 3) & 3;
        int so = (sb & 7) * 2;                   // byte offset within 16B chunk
#pragma unroll
        for (int nj = 0; nj < 4; nj++) {
          int dv = (wn & 1) * 64 + nj * 16 + l16;   // row 0..127 (head = dv>>6)
          int pc = (((dv & 1) << 2) | kc) ^ ((dv >> 1) & 7);
          float v0 = acc[mi][nj][0], v1 = acc[mi][nj][1], v2 = acc[mi][nj][2], v3 = acc[mi][nj][3];
          if (doElu) {
            v0 = (v0 > 0.0f) ? (v0 + 1.0f) : __expf(v0);
            v1 = (v1 > 0.0f) ? (v1 + 1.0f) : __expf(v1);
            v2 = (v2 > 0.0f) ? (v2 + 1.0f) : __expf(v2);
            v3 = (v3 > 0.0f) ? (v3 + 1.0f) : __expf(v3);
          }
          uint2 o;
          o.x = (unsigned)f2bf(v0) | ((unsigned)f2bf(v1) << 16);
          o.y = (unsigned)f2bf(v2) | ((unsigned)f2bf(v3) << 16);
          *(uint2*)(basekv + slot*8192 + (dv >> 1)*128 + pc*16 + so) = o;
        }
      }
    }
    __syncthreads();
    // 2) head-blocked KV: wave w -> head hh=w>>2, d-half dh=w&1, v-half vh=(w>>1)&1.
    int hh = w >> 2, dh = w & 1, vh = (w >> 1) & 1;
    short8 ones;
#pragma unroll
    for (int e = 0; e < 8; ++e) ones[e] = (short)0x3F80;   // bf16 1.0
    f32x4 a2[2][2], s2[2];
#pragma unroll
    for (int i = 0; i < 2; i++) {
      s2[i] = (f32x4)0.0f;
#pragma unroll
      for (int j = 0; j < 2; j++) a2[i][j] = (f32x4)0.0f;
    }
#pragma unroll
    for (int t = 0; t < 8; t++) {
      short8 ak[2], bv[2];
#pragma unroll
      for (int i = 0; i < 2; i++) {
        int d = hh * 64 + dh * 32 + i * 16 + l16;
        ak[i] = *(const short8*)(smemc + t*8192 + (d >> 1)*128 +
                                 (((((d & 1) << 2) | quad)) ^ ((d >> 1) & 7))*16);
        int v = hh * 64 + vh * 32 + i * 16 + l16;
        bv[i] = *(const short8*)(smemc + 65536 + t*8192 + (v >> 1)*128 +
                                 (((((v & 1) << 2) | quad)) ^ ((v >> 1) & 7))*16);
      }
#pragma unroll
      for (int i = 0; i < 2; i++) {
#pragma unroll
        for (int j = 0; j < 2; j++)
          a2[i][j] = __builtin_amdgcn_mfma_f32_16x16x32_bf16(ak[i], bv[j], a2[i][j], 0, 0, 0);
        if (vh == 0)
          s2[i] = __builtin_amdgcn_mfma_f32_16x16x32_bf16(ak[i], ones, s2[i], 0, 0, 0);
      }
    }
    // 3) plain partial stores: kvpp[mb*16 + p*2 + hh][dl*64+vl], kspp[...][dl]
    int p = bx;                 // head pair 0..7
    int mb = bm >> 8;           // M-block 0..63
    int b = bm >> 12;           // batch 0..3
    float* kdst = P1 + (size_t)(mb * 16 + p * 2 + hh) * 4096;
#pragma unroll
    for (int i = 0; i < 2; i++)
#pragma unroll
      for (int j = 0; j < 2; j++)
#pragma unroll
        for (int r = 0; r < 4; r++)
          kdst[(dh*32 + i*16 + quad*4 + r) * 64 + vh*32 + j*16 + l16] = a2[i][j][r];
    if (vh == 0 && l16 == 0) {
      float* sdst = P2 + (size_t)(mb * 16 + p * 2 + hh) * 64;
#pragma unroll
      for (int i = 0; i < 2; i++)
#pragma unroll
        for (int r = 0; r < 4; r++)
          sdst[dh*32 + i*16 + quad*4 + r] = s2[i][r];
    }
    // 4) last-block-per-(b,p): sum 16 partials, compute W~T slice + ksg (kvw absorbed).
    __threadfence();                         // release: partials visible device-wide
    if (tid == 0) lastFlag = (atomicAdd(&cnt[b * 8 + p], 1) == 15);
    __syncthreads();
    if (!lastFlag) return;
    __threadfence();                         // acquire: see all 16 blocks' partials
    u16* kv2 = (u16*)smemc;                  // [2 heads][64*64] bf16 (tiles are dead)
    for (int i = tid; i < 8192; i += 512) {
      int hh2 = i >> 12, idx = i & 4095;
      float s = 0.0f;
#pragma unroll
      for (int m = 0; m < 16; ++m)
        s += P1[(size_t)(((b * 16 + m) * 16) + p * 2 + hh2) * 4096 + idx];
      kv2[i] = f2bf(s);
    }
    if (tid < 128) {
      int hh2 = tid >> 6, d = tid & 63;
      float s = 0.0f;
#pragma unroll
      for (int m = 0; m < 16; ++m)
        s += P2[(size_t)(((b * 16 + m) * 16) + p * 2 + hh2) * 64 + d];
      ksgp[(b * 16 + p * 2 + hh2) * 64 + d] = s;
    }
    __syncthreads();
    // W~T for the pair's 2 heads (verified kvw body): wave w covers c rows
    // w*128 + cc*32; D[row=c, col=d] = sum_v Wo[h*64+v, c] * KV[d, v].
    u16* dst = wtp + ((size_t)b << 20);
#pragma unroll
    for (int hh2 = 0; hh2 < 2; ++hh2) {
      const u16* kvl = kv2 + hh2 * 4096;
      int hg = p * 2 + hh2;
      short8 bfr2[2][4];
#pragma unroll
      for (int ks = 0; ks < 2; ++ks)
#pragma unroll
        for (int nj = 0; nj < 4; ++nj)
          bfr2[ks][nj] = *(const short8*)(&kvl[(nj*16 + l16) * 64 + ks*32 + quad*8]);
#pragma unroll
      for (int cc = 0; cc < 4; ++cc) {
        int c0 = w * 128 + cc * 32;
        f32x4 acc2[2][4];
#pragma unroll
        for (int i = 0; i < 2; i++)
#pragma unroll
          for (int j = 0; j < 4; j++) acc2[i][j] = (f32x4)0.0f;
#pragma unroll
        for (int ks = 0; ks < 2; ++ks) {
#pragma unroll
          for (int mi = 0; mi < 2; ++mi) {
            short8 af2 = *(const short8*)(wotp + (size_t)(c0 + mi*16 + l16) * 1024
                                          + hg*64 + ks*32 + quad*8);
#pragma unroll
            for (int nj = 0; nj < 4; ++nj)
              acc2[mi][nj] = __builtin_amdgcn_mfma_f32_16x16x32_bf16(af2, bfr2[ks][nj],
                                                                     acc2[mi][nj], 0, 0, 0);
          }
        }
#pragma unroll
        for (int mi = 0; mi < 2; ++mi) {
          int c = c0 + mi*16 + quad*4;
#pragma unroll
          for (int nj = 0; nj < 4; ++nj) {
            int hd = hg*64 + nj*16 + l16;
#pragma unroll
            for (int r = 0; r < 4; ++r)
              dst[(size_t)(c + r) * 1024 + hd] = f2bf(acc2[mi][nj][r]);
          }
        }
      }
    }
  }
}

extern "C" void kernel_launch(void* const* d_in, const int* in_sizes, int n_in,
                              void* d_out, int out_size, void* d_ws, size_t ws_size,
                              hipStream_t stream) {
  const float* x    = (const float*)d_in[0];
  const float* Wqkv = (const float*)d_in[1];
  const float* Wo   = (const float*)d_in[2];
  float* out = (float*)d_out;
  char* ws = (char*)d_ws;
  if (ws_size < WS_NEEDED) return;  // visible failure, no corruption

  u16*   xb    = (u16*)  (ws + OFF_XB);
  u16*   wqkvt = (u16*)  (ws + OFF_WQKVT);
  u16*   wot   = (u16*)  (ws + OFF_WOT);
  u16*   qbuf  = (u16*)  (ws + OFF_QBUF);
  u16*   wt    = (u16*)  (ws + OFF_WT);
  float* ksg   = (float*)(ws + OFF_KSG);
  float* kvpp  = (float*)(ws + OFF_KVPP);
  float* kspp  = (float*)(ws + OFF_KSPP);
  int*   cnt   = (int*)  (ws + OFF_CNT);

  // prep: x->bf16, W transposes, counter zero (block 20480)
  prep_kernel<<<20481, 256, 0, stream>>>(x, xb, Wqkv, wqkvt, Wo, wot, cnt);
  // K/V columns: fused KV+Ksum partials; last block per (b,p) computes W~T + ksg
  gemm256<3><<<dim3(8, M_/256), 512, 0, stream>>>(xb, wqkvt, nullptr, nullptr, kvpp, kspp,
                                                  nullptr, wot, wt, ksg, cnt, M_, N1_, D_);
  // Q columns: elu+1 with fused per-head normalizer -> Q~ in qbuf
  gemm256<4><<<dim3(4, M_/256), 512, 0, stream>>>(xb, wqkvt, nullptr, qbuf, nullptr, nullptr,
                                                  ksg, nullptr, nullptr, nullptr, nullptr,
                                                  M_, N1_, D_);
  // out = Q~ @ W~_b (per-batch B via compile-time MODE=2), fp32 out
  gemm256<2><<<dim3(4, M_/256), 512, 0, stream>>>(qbuf, wt, out, nullptr, nullptr, nullptr,
                                                  nullptr, nullptr, nullptr, nullptr, nullptr,
                                                  M_, D_, D_);
}